// Round 2
// baseline (1332.644 us; speedup 1.0000x reference)
//
#include <hip/hip_runtime.h>
#include <math.h>

#define DEV_INLINE __device__ __forceinline__

DEV_INLINE float relu_f(float v) { return v > 0.f ? v : 0.f; }

DEV_INLINE void fma4(float4& a, float s, const float4& v) {
    a.x += s * v.x; a.y += s * v.y; a.z += s * v.z; a.w += s * v.w;
}

// ---------------------------------------------------------------------------
// conv1: x[32,152,152,3] * W[11,11,3,32] + b, relu -> y[32,142,142,32]
// block 256 (16ty x 16tx), tile 16 oh x 32 ow, thread: 2 ow x 32 oc
// LDS: W (46.4KB) + x tile 26x42x3 (13.1KB) = 59.6KB
// ---------------------------------------------------------------------------
__global__ __launch_bounds__(256, 2) void k_conv1(
    const float* __restrict__ x, const float* __restrict__ W,
    const float* __restrict__ b, float* __restrict__ y)
{
    __shared__ float sw[11 * 11 * 3 * 32];   // 11616
    __shared__ float sx[26 * 42 * 3];        // 3276
    const int n   = blockIdx.z;
    const int oh0 = blockIdx.y * 16;
    const int ow0 = blockIdx.x * 32;
    const int tid = threadIdx.x;

    for (int i = tid; i < 11616; i += 256) sw[i] = W[i];

    const float* xn = x + (size_t)n * 152 * 152 * 3;
    for (int i = tid; i < 26 * 42 * 3; i += 256) {
        int c = i % 3; int t = i / 3; int col = t % 42; int row = t / 42;
        int r  = oh0 + row; if (r > 151) r = 151;
        int cc = ow0 + col; if (cc > 151) cc = 151;
        sx[i] = xn[(r * 152 + cc) * 3 + c];
    }
    __syncthreads();

    const int ty = tid >> 4, tx = tid & 15;
    float acc[2][32];
#pragma unroll
    for (int p = 0; p < 2; ++p)
#pragma unroll
        for (int j = 0; j < 32; ++j) acc[p][j] = 0.f;

    for (int kh = 0; kh < 11; ++kh) {
        for (int kw = 0; kw < 11; ++kw) {
#pragma unroll
            for (int ic = 0; ic < 3; ++ic) {
                float x0 = sx[((ty + kh) * 42 + (tx + kw)) * 3 + ic];
                float x1 = sx[((ty + kh) * 42 + (tx + 16 + kw)) * 3 + ic];
                const float4* wp4 = (const float4*)&sw[((kh * 11 + kw) * 3 + ic) * 32];
#pragma unroll
                for (int j4 = 0; j4 < 8; ++j4) {
                    float4 w = wp4[j4];
                    acc[0][j4 * 4 + 0] += x0 * w.x;
                    acc[0][j4 * 4 + 1] += x0 * w.y;
                    acc[0][j4 * 4 + 2] += x0 * w.z;
                    acc[0][j4 * 4 + 3] += x0 * w.w;
                    acc[1][j4 * 4 + 0] += x1 * w.x;
                    acc[1][j4 * 4 + 1] += x1 * w.y;
                    acc[1][j4 * 4 + 2] += x1 * w.z;
                    acc[1][j4 * 4 + 3] += x1 * w.w;
                }
            }
        }
    }

#pragma unroll
    for (int p = 0; p < 2; ++p) {
        int oh = oh0 + ty, ow = ow0 + tx + p * 16;
        if (oh < 142 && ow < 142) {
            float* yp = y + (((size_t)n * 142 + oh) * 142 + ow) * 32;
#pragma unroll
            for (int j = 0; j < 32; ++j) yp[j] = relu_f(acc[p][j] + b[j]);
        }
    }
}

// ---------------------------------------------------------------------------
// maxpool 3x3 s2: y1[32,142,142,32] -> y2[32,70,70,32]
// ---------------------------------------------------------------------------
__global__ void k_pool(const float* __restrict__ x, float* __restrict__ y)
{
    int idx = blockIdx.x * 256 + threadIdx.x;  // over 32*70*70*8 (c in float4s)
    if (idx >= 32 * 70 * 70 * 8) return;
    int c4 = idx & 7; int t = idx >> 3;
    int pw = t % 70; t /= 70; int ph = t % 70; int n = t / 70;
    const float* xp = x + (((size_t)n * 142 + ph * 2) * 142 + pw * 2) * 32 + c4 * 4;
    float4 m = make_float4(-1e30f, -1e30f, -1e30f, -1e30f);
#pragma unroll
    for (int r = 0; r < 3; ++r) {
#pragma unroll
        for (int cc = 0; cc < 3; ++cc) {
            float4 v = *(const float4*)(xp + ((size_t)r * 142 + cc) * 32);
            m.x = fmaxf(m.x, v.x); m.y = fmaxf(m.y, v.y);
            m.z = fmaxf(m.z, v.z); m.w = fmaxf(m.w, v.w);
        }
    }
    *(float4*)(y + (size_t)idx * 4) = m;
}

// ---------------------------------------------------------------------------
// conv3: y2[32,70,70,32] * W[9,9,32,16] + b, relu -> y3[32,62,62,16]
// block 128 (8ty x 16tx), tile 8 oh x 32 ow, thread: 2 ow x 16 oc
// ic chunks of 8; LDS: w-chunk 41.5KB + x tile 16x40x8 20.5KB = 62KB
// ---------------------------------------------------------------------------
__global__ __launch_bounds__(128, 2) void k_conv3(
    const float* __restrict__ x, const float* __restrict__ W,
    const float* __restrict__ bias, float* __restrict__ y)
{
    __shared__ float sw[81 * 8 * 16];   // 10368
    __shared__ float sx[16 * 40 * 8];   // 5120
    const int n   = blockIdx.z;
    const int oh0 = blockIdx.y * 8;
    const int ow0 = blockIdx.x * 32;
    const int tid = threadIdx.x;
    const int ty = tid >> 4, tx = tid & 15;
    const float* xn = x + (size_t)n * 70 * 70 * 32;

    float acc[2][16];
#pragma unroll
    for (int p = 0; p < 2; ++p)
#pragma unroll
        for (int j = 0; j < 16; ++j) acc[p][j] = 0.f;

    for (int icc = 0; icc < 4; ++icc) {
        const int ic0 = icc * 8;
        __syncthreads();
        // stage W chunk: sw[q][ic][oc]
        for (int i = tid; i < 10368; i += 128) {
            int oc = i & 15; int t = i >> 4; int ic = t & 7; int q = t >> 3;
            sw[i] = W[(q * 32 + ic0 + ic) * 16 + oc];
        }
        // stage x tile: sx[row][col][ic]
        for (int i = tid; i < 5120; i += 128) {
            int ic = i & 7; int t = i >> 3; int col = t % 40; int row = t / 40;
            int r  = oh0 + row; if (r > 69) r = 69;
            int cc = ow0 + col; if (cc > 69) cc = 69;
            sx[i] = xn[(r * 70 + cc) * 32 + ic0 + ic];
        }
        __syncthreads();

        for (int kh = 0; kh < 9; ++kh) {
            for (int kw = 0; kw < 9; ++kw) {
                const int q = kh * 9 + kw;
#pragma unroll
                for (int ic = 0; ic < 8; ++ic) {
                    float x0 = sx[((ty + kh) * 40 + tx + kw) * 8 + ic];
                    float x1 = sx[((ty + kh) * 40 + tx + 16 + kw) * 8 + ic];
                    const float4* wp4 = (const float4*)&sw[(q * 8 + ic) * 16];
#pragma unroll
                    for (int j4 = 0; j4 < 4; ++j4) {
                        float4 w = wp4[j4];
                        acc[0][j4 * 4 + 0] += x0 * w.x;
                        acc[0][j4 * 4 + 1] += x0 * w.y;
                        acc[0][j4 * 4 + 2] += x0 * w.z;
                        acc[0][j4 * 4 + 3] += x0 * w.w;
                        acc[1][j4 * 4 + 0] += x1 * w.x;
                        acc[1][j4 * 4 + 1] += x1 * w.y;
                        acc[1][j4 * 4 + 2] += x1 * w.z;
                        acc[1][j4 * 4 + 3] += x1 * w.w;
                    }
                }
            }
        }
    }

#pragma unroll
    for (int p = 0; p < 2; ++p) {
        int oh = oh0 + ty, ow = ow0 + tx + p * 16;
        if (oh < 62 && ow < 62) {
            float* yp = y + (((size_t)n * 62 + oh) * 62 + ow) * 16;
#pragma unroll
            for (int j = 0; j < 16; ++j) yp[j] = relu_f(acc[p][j] + bias[j]);
        }
    }
}

// ---------------------------------------------------------------------------
// locally connected: one block (64 thr = 1 wave) per output position (i,j).
// thread = (b0, fq): handles batches b0 and b0+16, f = fq*4..fq*4+3.
// patch dim order (JAX conv_general_dilated_patches): p = c*K2 + kh*K + kw.
// We iterate q=(kh,kw) outer / c inner for x-line locality; weight slab per
// position is streamed from HBM exactly once (single wave per block).
// ---------------------------------------------------------------------------
template <int K, int S, int XD, int OD>
__global__ __launch_bounds__(64) void k_lc(
    const float* __restrict__ x, const float* __restrict__ W,
    const float* __restrict__ bias, float* __restrict__ y)
{
    constexpr int K2 = K * K;
    constexpr int P  = 16 * K2;
    __shared__ int soff[K2];
    const int i = blockIdx.y, j = blockIdx.x;
    const int tid = threadIdx.x;
    for (int t = tid; t < K2; t += 64) {
        int kh = t / K, kw = t % K;
        soff[t] = ((i * S + kh) * XD + (j * S + kw)) * 16;
    }
    __syncthreads();

    const int fq = tid & 3, b0 = tid >> 2;  // b0 in 0..15
    const float* xb0 = x + (size_t)b0 * XD * XD * 16;
    const float* xb1 = xb0 + (size_t)16 * XD * XD * 16;
    const float* wp  = W + ((size_t)(i * OD + j) * P) * 16 + fq * 4;

    float4 a0 = make_float4(0.f, 0.f, 0.f, 0.f);
    float4 a1 = make_float4(0.f, 0.f, 0.f, 0.f);

    for (int q = 0; q < K2; ++q) {
        const int ro = soff[q];
#pragma unroll
        for (int c4 = 0; c4 < 4; ++c4) {
            const float4 xv0 = *(const float4*)(xb0 + ro + c4 * 4);
            const float4 xv1 = *(const float4*)(xb1 + ro + c4 * 4);
            const float4 w0 = *(const float4*)(wp + ((c4 * 4 + 0) * K2 + q) * 16);
            const float4 w1 = *(const float4*)(wp + ((c4 * 4 + 1) * K2 + q) * 16);
            const float4 w2 = *(const float4*)(wp + ((c4 * 4 + 2) * K2 + q) * 16);
            const float4 w3 = *(const float4*)(wp + ((c4 * 4 + 3) * K2 + q) * 16);
            fma4(a0, xv0.x, w0); fma4(a0, xv0.y, w1); fma4(a0, xv0.z, w2); fma4(a0, xv0.w, w3);
            fma4(a1, xv1.x, w0); fma4(a1, xv1.y, w1); fma4(a1, xv1.z, w2); fma4(a1, xv1.w, w3);
        }
    }

    const float4 bv = *(const float4*)(bias + ((size_t)i * OD + j) * 16 + fq * 4);
    a0.x = relu_f(a0.x + bv.x); a0.y = relu_f(a0.y + bv.y);
    a0.z = relu_f(a0.z + bv.z); a0.w = relu_f(a0.w + bv.w);
    a1.x = relu_f(a1.x + bv.x); a1.y = relu_f(a1.y + bv.y);
    a1.z = relu_f(a1.z + bv.z); a1.w = relu_f(a1.w + bv.w);
    *(float4*)(y + (((size_t)b0 * OD + i) * OD + j) * 16 + fq * 4) = a0;
    *(float4*)(y + (((size_t)(b0 + 16) * OD + i) * OD + j) * 16 + fq * 4) = a1;
}

// ---------------------------------------------------------------------------
// FC7 split-K: x[32,6400] @ W7[6400,4096] -> partials [16kb][32][4096]
// grid (16 ob, 16 kb), block 256; thread = one o, acc over 32 batches.
// x loads are wave-uniform (scalarizable); W loads coalesced.
// ---------------------------------------------------------------------------
__global__ __launch_bounds__(256) void k_fc7(
    const float* __restrict__ x, const float* __restrict__ W,
    float* __restrict__ part)
{
    const int o  = blockIdx.x * 256 + threadIdx.x;
    const int k0 = blockIdx.y * 400;
    float acc[32];
#pragma unroll
    for (int b = 0; b < 32; ++b) acc[b] = 0.f;
    const float* wp = W + (size_t)k0 * 4096 + o;
    for (int kk = 0; kk < 400; kk += 2) {
        float w0 = wp[(size_t)kk * 4096];
        float w1 = wp[(size_t)(kk + 1) * 4096];
#pragma unroll
        for (int b = 0; b < 32; ++b) {
            float2 xv = *(const float2*)(x + (size_t)b * 6400 + k0 + kk);
            acc[b] += xv.x * w0 + xv.y * w1;
        }
    }
    float* pp = part + ((size_t)blockIdx.y * 32) * 4096 + o;
#pragma unroll
    for (int b = 0; b < 32; ++b) pp[(size_t)b * 4096] = acc[b];
}

// ---------------------------------------------------------------------------
// reduce partials + b7 + relu, dot with W8, + b8, sigmoid -> out[32]
// ---------------------------------------------------------------------------
__global__ __launch_bounds__(256) void k_fc8(
    const float* __restrict__ part, const float* __restrict__ b7,
    const float* __restrict__ W8, const float* __restrict__ b8,
    float* __restrict__ out)
{
    const int b = blockIdx.x, tid = threadIdx.x;
    float s = 0.f;
    for (int o = tid; o < 4096; o += 256) {
        float v = b7[o];
#pragma unroll
        for (int kb = 0; kb < 16; ++kb) v += part[((size_t)kb * 32 + b) * 4096 + o];
        v = relu_f(v);
        s += v * W8[o];
    }
#pragma unroll
    for (int off = 32; off > 0; off >>= 1) s += __shfl_down(s, off, 64);
    __shared__ float red[4];
    if ((tid & 63) == 0) red[tid >> 6] = s;
    __syncthreads();
    if (tid == 0) {
        float t = red[0] + red[1] + red[2] + red[3] + b8[0];
        out[b] = 1.f / (1.f + expf(-t));
    }
}

// ---------------------------------------------------------------------------
extern "C" void kernel_launch(void* const* d_in, const int* in_sizes, int n_in,
                              void* d_out, int out_size, void* d_ws, size_t ws_size,
                              hipStream_t stream)
{
    (void)in_sizes; (void)n_in; (void)out_size; (void)ws_size;
    const float* x   = (const float*)d_in[0];
    const float* W1  = (const float*)d_in[1];
    const float* b1  = (const float*)d_in[2];
    const float* W3  = (const float*)d_in[3];
    const float* b3  = (const float*)d_in[4];
    const float* LW4 = (const float*)d_in[5];
    const float* Lb4 = (const float*)d_in[6];
    const float* LW5 = (const float*)d_in[7];
    const float* Lb5 = (const float*)d_in[8];
    const float* LW6 = (const float*)d_in[9];
    const float* Lb6 = (const float*)d_in[10];
    const float* W7  = (const float*)d_in[11];
    const float* b7  = (const float*)d_in[12];
    const float* W8  = (const float*)d_in[13];
    const float* b8  = (const float*)d_in[14];
    float* out = (float*)d_out;

    float* ws = (float*)d_ws;
    // workspace layout (floats); y3..p7 overlay dead y1 region. peak ~25.7M fl.
    float* y1 = ws;                    // 32*142*142*32 = 20,647,936
    float* y2 = ws + 20647936;         // 32*70*70*32   =  5,017,600
    float* y3 = ws;                    // 32*62*62*16   =  1,968,128
    float* y4 = ws + 1968128;          // 32*54*54*16   =  1,492,992
    float* y5 = ws + 3461120;          // 32*24*24*16   =    294,912
    float* y6 = ws + 3756032;          // 32*20*20*16   =    204,800
    float* p7 = ws + 3960832;          // 16*32*4096    =  2,097,152

    k_conv1<<<dim3(5, 9, 32), 256, 0, stream>>>(x, W1, b1, y1);
    k_pool<<<dim3(4900), 256, 0, stream>>>(y1, y2);
    k_conv3<<<dim3(2, 8, 32), 128, 0, stream>>>(y2, W3, b3, y3);
    k_lc<9, 1, 62, 54><<<dim3(54, 54), 64, 0, stream>>>(y3, LW4, Lb4, y4);
    k_lc<7, 2, 54, 24><<<dim3(24, 24), 64, 0, stream>>>(y4, LW5, Lb5, y5);
    k_lc<5, 1, 24, 20><<<dim3(20, 20), 64, 0, stream>>>(y5, LW6, Lb6, y6);
    k_fc7<<<dim3(16, 16), 256, 0, stream>>>(y6, W7, p7);
    k_fc8<<<dim3(32), 256, 0, stream>>>(p7, b7, W8, b8, out);
}

// Round 3
// 1170.007 us; speedup vs baseline: 1.1390x; 1.1390x over previous
//
#include <hip/hip_runtime.h>
#include <math.h>

#define DEV_INLINE __device__ __forceinline__

DEV_INLINE float relu_f(float v) { return v > 0.f ? v : 0.f; }

DEV_INLINE void fma4(float4& a, float s, const float4& v) {
    a.x += s * v.x; a.y += s * v.y; a.z += s * v.z; a.w += s * v.w;
}

// ---------------------------------------------------------------------------
// conv1: x[32,152,152,3] * W[11,11,3,32] + b, relu -> y[32,142,142,32]
// block 256 (16ty x 16tx), tile 16 oh x 32 ow, thread: 2 ow x 32 oc
// LDS: W (46.4KB) + x tile 26x42x3 (13.1KB) = 59.6KB
// ---------------------------------------------------------------------------
__global__ __launch_bounds__(256, 2) void k_conv1(
    const float* __restrict__ x, const float* __restrict__ W,
    const float* __restrict__ b, float* __restrict__ y)
{
    __shared__ float sw[11 * 11 * 3 * 32];   // 11616
    __shared__ float sx[26 * 42 * 3];        // 3276
    const int n   = blockIdx.z;
    const int oh0 = blockIdx.y * 16;
    const int ow0 = blockIdx.x * 32;
    const int tid = threadIdx.x;

    for (int i = tid; i < 11616; i += 256) sw[i] = W[i];

    const float* xn = x + (size_t)n * 152 * 152 * 3;
    for (int i = tid; i < 26 * 42 * 3; i += 256) {
        int c = i % 3; int t = i / 3; int col = t % 42; int row = t / 42;
        int r  = oh0 + row; if (r > 151) r = 151;
        int cc = ow0 + col; if (cc > 151) cc = 151;
        sx[i] = xn[(r * 152 + cc) * 3 + c];
    }
    __syncthreads();

    const int ty = tid >> 4, tx = tid & 15;
    float acc[2][32];
#pragma unroll
    for (int p = 0; p < 2; ++p)
#pragma unroll
        for (int j = 0; j < 32; ++j) acc[p][j] = 0.f;

    for (int kh = 0; kh < 11; ++kh) {
        for (int kw = 0; kw < 11; ++kw) {
#pragma unroll
            for (int ic = 0; ic < 3; ++ic) {
                float x0 = sx[((ty + kh) * 42 + (tx + kw)) * 3 + ic];
                float x1 = sx[((ty + kh) * 42 + (tx + 16 + kw)) * 3 + ic];
                const float4* wp4 = (const float4*)&sw[((kh * 11 + kw) * 3 + ic) * 32];
#pragma unroll
                for (int j4 = 0; j4 < 8; ++j4) {
                    float4 w = wp4[j4];
                    acc[0][j4 * 4 + 0] += x0 * w.x;
                    acc[0][j4 * 4 + 1] += x0 * w.y;
                    acc[0][j4 * 4 + 2] += x0 * w.z;
                    acc[0][j4 * 4 + 3] += x0 * w.w;
                    acc[1][j4 * 4 + 0] += x1 * w.x;
                    acc[1][j4 * 4 + 1] += x1 * w.y;
                    acc[1][j4 * 4 + 2] += x1 * w.z;
                    acc[1][j4 * 4 + 3] += x1 * w.w;
                }
            }
        }
    }

#pragma unroll
    for (int p = 0; p < 2; ++p) {
        int oh = oh0 + ty, ow = ow0 + tx + p * 16;
        if (oh < 142 && ow < 142) {
            float* yp = y + (((size_t)n * 142 + oh) * 142 + ow) * 32;
#pragma unroll
            for (int j = 0; j < 32; ++j) yp[j] = relu_f(acc[p][j] + b[j]);
        }
    }
}

// ---------------------------------------------------------------------------
// maxpool 3x3 s2: y1[32,142,142,32] -> y2[32,70,70,32]
// ---------------------------------------------------------------------------
__global__ void k_pool(const float* __restrict__ x, float* __restrict__ y)
{
    int idx = blockIdx.x * 256 + threadIdx.x;  // over 32*70*70*8 (c in float4s)
    if (idx >= 32 * 70 * 70 * 8) return;
    int c4 = idx & 7; int t = idx >> 3;
    int pw = t % 70; t /= 70; int ph = t % 70; int n = t / 70;
    const float* xp = x + (((size_t)n * 142 + ph * 2) * 142 + pw * 2) * 32 + c4 * 4;
    float4 m = make_float4(-1e30f, -1e30f, -1e30f, -1e30f);
#pragma unroll
    for (int r = 0; r < 3; ++r) {
#pragma unroll
        for (int cc = 0; cc < 3; ++cc) {
            float4 v = *(const float4*)(xp + ((size_t)r * 142 + cc) * 32);
            m.x = fmaxf(m.x, v.x); m.y = fmaxf(m.y, v.y);
            m.z = fmaxf(m.z, v.z); m.w = fmaxf(m.w, v.w);
        }
    }
    *(float4*)(y + (size_t)idx * 4) = m;
}

// ---------------------------------------------------------------------------
// conv3: y2[32,70,70,32] * W[9,9,32,16] + b, relu -> y3[32,62,62,16]
// block 128 (8ty x 16tx), tile 8 oh x 32 ow, thread: 2 ow x 16 oc
// ic chunks of 8; LDS: w-chunk 41.5KB + x tile 16x40x8 20.5KB = 62KB
// ---------------------------------------------------------------------------
__global__ __launch_bounds__(128, 2) void k_conv3(
    const float* __restrict__ x, const float* __restrict__ W,
    const float* __restrict__ bias, float* __restrict__ y)
{
    __shared__ float sw[81 * 8 * 16];   // 10368
    __shared__ float sx[16 * 40 * 8];   // 5120
    const int n   = blockIdx.z;
    const int oh0 = blockIdx.y * 8;
    const int ow0 = blockIdx.x * 32;
    const int tid = threadIdx.x;
    const int ty = tid >> 4, tx = tid & 15;
    const float* xn = x + (size_t)n * 70 * 70 * 32;

    float acc[2][16];
#pragma unroll
    for (int p = 0; p < 2; ++p)
#pragma unroll
        for (int j = 0; j < 16; ++j) acc[p][j] = 0.f;

    for (int icc = 0; icc < 4; ++icc) {
        const int ic0 = icc * 8;
        __syncthreads();
        // stage W chunk: sw[q][ic][oc]
        for (int i = tid; i < 10368; i += 128) {
            int oc = i & 15; int t = i >> 4; int ic = t & 7; int q = t >> 3;
            sw[i] = W[(q * 32 + ic0 + ic) * 16 + oc];
        }
        // stage x tile: sx[row][col][ic]
        for (int i = tid; i < 5120; i += 128) {
            int ic = i & 7; int t = i >> 3; int col = t % 40; int row = t / 40;
            int r  = oh0 + row; if (r > 69) r = 69;
            int cc = ow0 + col; if (cc > 69) cc = 69;
            sx[i] = xn[(r * 70 + cc) * 32 + ic0 + ic];
        }
        __syncthreads();

        for (int kh = 0; kh < 9; ++kh) {
            for (int kw = 0; kw < 9; ++kw) {
                const int q = kh * 9 + kw;
#pragma unroll
                for (int ic = 0; ic < 8; ++ic) {
                    float x0 = sx[((ty + kh) * 40 + tx + kw) * 8 + ic];
                    float x1 = sx[((ty + kh) * 40 + tx + 16 + kw) * 8 + ic];
                    const float4* wp4 = (const float4*)&sw[(q * 8 + ic) * 16];
#pragma unroll
                    for (int j4 = 0; j4 < 4; ++j4) {
                        float4 w = wp4[j4];
                        acc[0][j4 * 4 + 0] += x0 * w.x;
                        acc[0][j4 * 4 + 1] += x0 * w.y;
                        acc[0][j4 * 4 + 2] += x0 * w.z;
                        acc[0][j4 * 4 + 3] += x0 * w.w;
                        acc[1][j4 * 4 + 0] += x1 * w.x;
                        acc[1][j4 * 4 + 1] += x1 * w.y;
                        acc[1][j4 * 4 + 2] += x1 * w.z;
                        acc[1][j4 * 4 + 3] += x1 * w.w;
                    }
                }
            }
        }
    }

#pragma unroll
    for (int p = 0; p < 2; ++p) {
        int oh = oh0 + ty, ow = ow0 + tx + p * 16;
        if (oh < 62 && ow < 62) {
            float* yp = y + (((size_t)n * 62 + oh) * 62 + ow) * 16;
#pragma unroll
            for (int j = 0; j < 16; ++j) yp[j] = relu_f(acc[p][j] + bias[j]);
        }
    }
}

// ---------------------------------------------------------------------------
// locally connected v2: block = one output position (i,j), 128 threads
// (2 waves). thread = (b = tid>>2 in 0..31, f4 = tid&3). Weight slab for the
// position is staged global->LDS in STAGES contiguous chunks of GC channels
// (p = c*K2+q is linear in memory, so each chunk is one contiguous span ->
// perfectly coalesced float4 staging, 1KB/wave-inst). Compute reads x as
// c-contiguous float4 from global (L1/L2-resident activations) and weights
// from LDS via ds_read_b128 (16-way same-address broadcast = conflict-free).
// Each thread owns its full K-sum: no cross-lane reduction.
// ---------------------------------------------------------------------------
template <int K, int S, int XD, int OD, int GC>
__global__ __launch_bounds__(128) void k_lc(
    const float* __restrict__ x, const float* __restrict__ W,
    const float* __restrict__ bias, float* __restrict__ y)
{
    constexpr int K2     = K * K;
    constexpr int STAGES = 16 / GC;
    constexpr int SPAN4  = GC * K2 * 4;       // float4s per stage
    __shared__ float sw[GC * K2 * 16];        // <= 25.6 KB

    const int i = blockIdx.y, j = blockIdx.x;
    const int tid = threadIdx.x;
    const int f4 = tid & 3, b = tid >> 2;     // b in 0..31

    const float* xb = x + ((size_t)b * XD * XD + (size_t)(i * S) * XD + (j * S)) * 16;
    const float4* wsrc_base = (const float4*)(W + (size_t)(i * OD + j) * (K2 * 16) * 16);

    float4 acc = make_float4(0.f, 0.f, 0.f, 0.f);

    for (int st = 0; st < STAGES; ++st) {
        const int c0 = st * GC;
        __syncthreads();
        const float4* wsrc = wsrc_base + (size_t)c0 * K2 * 4;
        for (int t = tid; t < SPAN4; t += 128)
            ((float4*)sw)[t] = wsrc[t];
        __syncthreads();

        for (int kh = 0; kh < K; ++kh) {
            const float* xrow = xb + (size_t)(kh * XD) * 16 + c0;
            for (int kw = 0; kw < K; ++kw) {
                const int q = kh * K + kw;
                const float* xr = xrow + kw * 16;
#pragma unroll
                for (int cq = 0; cq < GC / 4; ++cq) {
                    const float4 xv = *(const float4*)(xr + cq * 4);
                    const int cb = cq * 4;
                    fma4(acc, xv.x, *(const float4*)&sw[((cb + 0) * K2 + q) * 16 + f4 * 4]);
                    fma4(acc, xv.y, *(const float4*)&sw[((cb + 1) * K2 + q) * 16 + f4 * 4]);
                    fma4(acc, xv.z, *(const float4*)&sw[((cb + 2) * K2 + q) * 16 + f4 * 4]);
                    fma4(acc, xv.w, *(const float4*)&sw[((cb + 3) * K2 + q) * 16 + f4 * 4]);
                }
            }
        }
    }

    const float4 bv = *(const float4*)(bias + ((size_t)i * OD + j) * 16 + f4 * 4);
    acc.x = relu_f(acc.x + bv.x); acc.y = relu_f(acc.y + bv.y);
    acc.z = relu_f(acc.z + bv.z); acc.w = relu_f(acc.w + bv.w);
    *(float4*)(y + (((size_t)b * OD + i) * OD + j) * 16 + f4 * 4) = acc;
}

// ---------------------------------------------------------------------------
// FC7 split-K: x[32,6400] @ W7[6400,4096] -> partials [16kb][32][4096]
// ---------------------------------------------------------------------------
__global__ __launch_bounds__(256) void k_fc7(
    const float* __restrict__ x, const float* __restrict__ W,
    float* __restrict__ part)
{
    const int o  = blockIdx.x * 256 + threadIdx.x;
    const int k0 = blockIdx.y * 400;
    float acc[32];
#pragma unroll
    for (int b = 0; b < 32; ++b) acc[b] = 0.f;
    const float* wp = W + (size_t)k0 * 4096 + o;
    for (int kk = 0; kk < 400; kk += 2) {
        float w0 = wp[(size_t)kk * 4096];
        float w1 = wp[(size_t)(kk + 1) * 4096];
#pragma unroll
        for (int b = 0; b < 32; ++b) {
            float2 xv = *(const float2*)(x + (size_t)b * 6400 + k0 + kk);
            acc[b] += xv.x * w0 + xv.y * w1;
        }
    }
    float* pp = part + ((size_t)blockIdx.y * 32) * 4096 + o;
#pragma unroll
    for (int b = 0; b < 32; ++b) pp[(size_t)b * 4096] = acc[b];
}

// ---------------------------------------------------------------------------
// reduce partials + b7 + relu, dot with W8, + b8, sigmoid -> out[32]
// ---------------------------------------------------------------------------
__global__ __launch_bounds__(256) void k_fc8(
    const float* __restrict__ part, const float* __restrict__ b7,
    const float* __restrict__ W8, const float* __restrict__ b8,
    float* __restrict__ out)
{
    const int b = blockIdx.x, tid = threadIdx.x;
    float s = 0.f;
    for (int o = tid; o < 4096; o += 256) {
        float v = b7[o];
#pragma unroll
        for (int kb = 0; kb < 16; ++kb) v += part[((size_t)kb * 32 + b) * 4096 + o];
        v = relu_f(v);
        s += v * W8[o];
    }
#pragma unroll
    for (int off = 32; off > 0; off >>= 1) s += __shfl_down(s, off, 64);
    __shared__ float red[4];
    if ((tid & 63) == 0) red[tid >> 6] = s;
    __syncthreads();
    if (tid == 0) {
        float t = red[0] + red[1] + red[2] + red[3] + b8[0];
        out[b] = 1.f / (1.f + expf(-t));
    }
}

// ---------------------------------------------------------------------------
extern "C" void kernel_launch(void* const* d_in, const int* in_sizes, int n_in,
                              void* d_out, int out_size, void* d_ws, size_t ws_size,
                              hipStream_t stream)
{
    (void)in_sizes; (void)n_in; (void)out_size; (void)ws_size;
    const float* x   = (const float*)d_in[0];
    const float* W1  = (const float*)d_in[1];
    const float* b1  = (const float*)d_in[2];
    const float* W3  = (const float*)d_in[3];
    const float* b3  = (const float*)d_in[4];
    const float* LW4 = (const float*)d_in[5];
    const float* Lb4 = (const float*)d_in[6];
    const float* LW5 = (const float*)d_in[7];
    const float* Lb5 = (const float*)d_in[8];
    const float* LW6 = (const float*)d_in[9];
    const float* Lb6 = (const float*)d_in[10];
    const float* W7  = (const float*)d_in[11];
    const float* b7  = (const float*)d_in[12];
    const float* W8  = (const float*)d_in[13];
    const float* b8  = (const float*)d_in[14];
    float* out = (float*)d_out;

    float* ws = (float*)d_ws;
    // workspace layout (floats); y3..p7 overlay dead y1 region.
    float* y1 = ws;                    // 32*142*142*32 = 20,647,936
    float* y2 = ws + 20647936;         // 32*70*70*32   =  5,017,600
    float* y3 = ws;                    // 32*62*62*16   =  1,968,128
    float* y4 = ws + 1968128;          // 32*54*54*16   =  1,492,992
    float* y5 = ws + 3461120;          // 32*24*24*16   =    294,912
    float* y6 = ws + 3756032;          // 32*20*20*16   =    204,800
    float* p7 = ws + 3960832;          // 16*32*4096    =  2,097,152

    k_conv1<<<dim3(5, 9, 32), 256, 0, stream>>>(x, W1, b1, y1);
    k_pool<<<dim3(4900), 256, 0, stream>>>(y1, y2);
    k_conv3<<<dim3(2, 8, 32), 128, 0, stream>>>(y2, W3, b3, y3);
    k_lc<9, 1, 62, 54, 4><<<dim3(54, 54), 128, 0, stream>>>(y3, LW4, Lb4, y4);
    k_lc<7, 2, 54, 24, 8><<<dim3(24, 24), 128, 0, stream>>>(y4, LW5, Lb5, y5);
    k_lc<5, 1, 24, 20, 16><<<dim3(20, 20), 128, 0, stream>>>(y5, LW6, Lb6, y6);
    k_fc7<<<dim3(16, 16), 256, 0, stream>>>(y6, W7, p7);
    k_fc8<<<dim3(32), 256, 0, stream>>>(p7, b7, W8, b8, out);
}